// Round 10
// baseline (289.798 us; speedup 1.0000x reference)
//
#include <hip/hip_runtime.h>
#include <math.h>

#define D_X      1024
#define D_TEXT   768
#define FDIM     1792
#define BATCH    256
#define M_EXP    16
#define HW_TOT   1024   // 32*32

// Output layout (flat f32): gates[4096] | moe_loss[1] | probs[4096] | top_idx[512]
#define OUT_GATES 0
#define OUT_LOSS  4096
#define OUT_PROBS 4097
#define OUT_IDX   8193

#define NBLK_DEG 224
#define NCH      16                    // K-chunks of the pooled half
#define CHW      64                    // channels per chunk
#define NBLK_PG  (NCH * BATCH)         // 4096 pool+GEMM blocks, b fastest
#define GRID1    (NBLK_DEG + NBLK_PG)

// ---------------------------------------------------------------------------
// Kernel 1 (role-split):
//   blocks [0, 224):     deg-GEMM  pact2 = degraded @ W[1024:, :]  (R5-proven)
//   blocks [224, 4320):  pool 64 channels of one batch row -> vs[64] in LDS,
//                        then pslice[chunk][b][:] = vs @ W[chunk*64:+64, :]
//                        (block-local: no cross-block sync of any kind)
// ---------------------------------------------------------------------------
__global__ __launch_bounds__(256) void pool_gemm_kernel(const float* __restrict__ x,
                                                        const float* __restrict__ deg,
                                                        const float* __restrict__ W,
                                                        float* __restrict__ pslice,
                                                        float* __restrict__ pact2) {
    __shared__ float As1[32][33];   // deg tile, transposed [k][m]
    __shared__ float Ws1[32][64];   // W tile [k][n]
    __shared__ float vs[CHW];       // pooled chunk values

    const int bid = blockIdx.x;
    const int tid = threadIdx.x;

    if (bid >= NBLK_DEG) {
        // ---- pool+GEMM path ----
        const int pb    = bid - NBLK_DEG;
        const int chunk = pb >> 8;          // 0..15  (b fastest -> W slice shared)
        const int b     = pb & 255;
        const int w     = tid >> 6;
        const int lane  = tid & 63;

        // pool phase: wave w pools local channels [w*16, w*16+16), 2 rows in flight
        for (int rp = 0; rp < 8; ++rp) {
            const int cl = w * 16 + rp * 2;
            const float4* x0 = reinterpret_cast<const float4*>(
                x + ((size_t)b * D_X + chunk * CHW + cl) * HW_TOT);
            float4 v0[4], v1[4];
#pragma unroll
            for (int k = 0; k < 4; ++k) v0[k] = x0[k * 64 + lane];
#pragma unroll
            for (int k = 0; k < 4; ++k) v1[k] = x0[256 + k * 64 + lane];
            float s0 = 0.0f, s1 = 0.0f;
#pragma unroll
            for (int k = 0; k < 4; ++k) {
                s0 += v0[k].x + v0[k].y + v0[k].z + v0[k].w;
                s1 += v1[k].x + v1[k].y + v1[k].z + v1[k].w;
            }
#pragma unroll
            for (int off = 32; off > 0; off >>= 1) {
                s0 += __shfl_xor(s0, off, 64);
                s1 += __shfl_xor(s1, off, 64);
            }
            if (lane == 0) {
                vs[cl]     = s0 * (1.0f / 1024.0f);
                vs[cl + 1] = s1 * (1.0f / 1024.0f);
            }
        }
        __syncthreads();

        // GEMM phase: pslice[chunk][b][n] = sum_c vs[c] * W[chunk*64+c][n]
        // thread owns n = tid + j*256 for j=0..6 (coalesced)
        float s[7] = {};
        const float* wb = W + (size_t)(chunk * CHW) * FDIM + tid;
#pragma unroll 4
        for (int c = 0; c < CHW; ++c) {
            const float v = vs[c];                       // LDS broadcast
            const float* wr = wb + (size_t)c * FDIM;
#pragma unroll
            for (int j = 0; j < 7; ++j) s[j] = fmaf(v, wr[j * 256], s[j]);
        }
        float* po = pslice + ((size_t)chunk * BATCH + b) * FDIM + tid;
#pragma unroll
        for (int j = 0; j < 7; ++j) po[j * 256] = s[j];
        return;
    }

    // ---- deg-GEMM path: 32m x 64n tile, BK=32, 24 iters (verbatim R5) ----
    const int mb = bid / 28;
    const int nb = bid % 28;
    const int m0 = mb * 32;
    const int n0 = nb * 64;

    const int tx = tid & 15;        // n-groups of 4
    const int ty = tid >> 4;        // m-groups of 2

    const int ar  = tid >> 3;       // A row 0..31
    const int ak4 = (tid & 7) * 4;  // A k-col
    const int wk  = tid >> 4;       // W k-row (+16 for second)
    const int wc4 = (tid & 15) * 4; // W n-col

    float acc[2][4] = {};

    for (int k0 = 0; k0 < D_TEXT; k0 += 32) {
        __syncthreads();
        {
            const float4 a = *reinterpret_cast<const float4*>(
                deg + (size_t)(m0 + ar) * D_TEXT + k0 + ak4);
            As1[ak4 + 0][ar] = a.x; As1[ak4 + 1][ar] = a.y;
            As1[ak4 + 2][ar] = a.z; As1[ak4 + 3][ar] = a.w;
            *reinterpret_cast<float4*>(&Ws1[wk][wc4]) =
                *reinterpret_cast<const float4*>(W + (size_t)(D_X + k0 + wk) * FDIM + n0 + wc4);
            *reinterpret_cast<float4*>(&Ws1[wk + 16][wc4]) =
                *reinterpret_cast<const float4*>(W + (size_t)(D_X + k0 + wk + 16) * FDIM + n0 + wc4);
        }
        __syncthreads();
#pragma unroll
        for (int kk = 0; kk < 32; ++kk) {
            const float2 a = *reinterpret_cast<const float2*>(&As1[kk][ty * 2]);
            const float4 w = *reinterpret_cast<const float4*>(&Ws1[kk][tx * 4]);
            acc[0][0] = fmaf(a.x, w.x, acc[0][0]);
            acc[0][1] = fmaf(a.x, w.y, acc[0][1]);
            acc[0][2] = fmaf(a.x, w.z, acc[0][2]);
            acc[0][3] = fmaf(a.x, w.w, acc[0][3]);
            acc[1][0] = fmaf(a.y, w.x, acc[1][0]);
            acc[1][1] = fmaf(a.y, w.y, acc[1][1]);
            acc[1][2] = fmaf(a.y, w.z, acc[1][2]);
            acc[1][3] = fmaf(a.y, w.w, acc[1][3]);
        }
    }

#pragma unroll
    for (int i = 0; i < 2; ++i) {
        float4 v;
        v.x = acc[i][0]; v.y = acc[i][1]; v.z = acc[i][2]; v.w = acc[i][3];
        *reinterpret_cast<float4*>(pact2 + (size_t)(m0 + ty * 2 + i) * FDIM + n0 + tx * 4) = v;
    }
}

// ---------------------------------------------------------------------------
// Kernel 2: act = gelu(sum_ch pslice[ch] + pact2 + bias) tile -> gate partials
// + last-block finalize (R9-proven). Grid (8, 28), 256 threads.
// ---------------------------------------------------------------------------
#define BM 32
#define BN 64

__global__ __launch_bounds__(256) void reduce_gate_kernel(const float* __restrict__ pslice,
                                                          const float* __restrict__ pact2,
                                                          const float* __restrict__ bias,
                                                          const float* __restrict__ wg,
                                                          float* __restrict__ part,
                                                          int* __restrict__ done,
                                                          float* __restrict__ out) {
    __shared__ float actS[BM][BN + 1];
    __shared__ float wgs[BN][M_EXP];
    __shared__ int isLast;

    const int tid = threadIdx.x;
    const int m0 = blockIdx.x * BM;
    const int n0 = blockIdx.y * BN;

    // wg slab: 64 rows x 16 = 256 float4
    {
        const int r  = tid >> 2;
        const int c4 = (tid & 3) * 4;
        *reinterpret_cast<float4*>(&wgs[r][c4]) =
            *reinterpret_cast<const float4*>(wg + (size_t)(n0 + r) * M_EXP + c4);
    }

    // thread owns row m = tid>>3, cols n8..n8+7
    const int m  = tid >> 3;             // 0..31
    const int n8 = (tid & 7) * 8;        // 0..56
    const size_t rowoff = (size_t)(m0 + m) * FDIM + n0 + n8;

    float vv[8];
    {
        const float4 p0 = *reinterpret_cast<const float4*>(pact2 + rowoff);
        const float4 p1 = *reinterpret_cast<const float4*>(pact2 + rowoff + 4);
        const float4 b0 = *reinterpret_cast<const float4*>(bias + n0 + n8);
        const float4 b1 = *reinterpret_cast<const float4*>(bias + n0 + n8 + 4);
        vv[0] = p0.x + b0.x; vv[1] = p0.y + b0.y; vv[2] = p0.z + b0.z; vv[3] = p0.w + b0.w;
        vv[4] = p1.x + b1.x; vv[5] = p1.y + b1.y; vv[6] = p1.z + b1.z; vv[7] = p1.w + b1.w;
    }
    // fixed-order chunk reduction (deterministic)
    for (int ch = 0; ch < NCH; ++ch) {
        const float4 q0 = *reinterpret_cast<const float4*>(
            pslice + (size_t)ch * BATCH * FDIM + rowoff);
        const float4 q1 = *reinterpret_cast<const float4*>(
            pslice + (size_t)ch * BATCH * FDIM + rowoff + 4);
        vv[0] += q0.x; vv[1] += q0.y; vv[2] += q0.z; vv[3] += q0.w;
        vv[4] += q1.x; vv[5] += q1.y; vv[6] += q1.z; vv[7] += q1.w;
    }
#pragma unroll
    for (int j = 0; j < 8; ++j)
        actS[m][n8 + j] = vv[j] * 0.5f * (1.0f + erff(vv[j] * 0.70710678118654752440f));
    __syncthreads();

    // gate partials: 32 rows x 16 experts, 2 per thread (R2-proven)
    const int pm = tid >> 3;
    const int pe = (tid & 7) * 2;
    float s0 = 0.0f, s1 = 0.0f;
#pragma unroll
    for (int n = 0; n < BN; ++n) {
        const float a = actS[pm][n];
        s0 = fmaf(a, wgs[n][pe], s0);
        s1 = fmaf(a, wgs[n][pe + 1], s1);
    }
    float* pr = part + ((size_t)blockIdx.y * BATCH + m0 + pm) * M_EXP + pe;
    pr[0] = s0;
    pr[1] = s1;

    // ---- last-block finalize (R9-proven: no polling, one ACQ_REL RMW) ----
    __threadfence();
    __syncthreads();
    if (tid == 0) {
        const int prev = __hip_atomic_fetch_add(done, 1, __ATOMIC_ACQ_REL,
                                                __HIP_MEMORY_SCOPE_AGENT);
        isLast = (prev == 8 * 28 - 1);
    }
    __syncthreads();
    if (!isLast) return;

    {
        const int b = tid;    // 256 threads = 256 rows
        float l[M_EXP];
#pragma unroll
        for (int mm = 0; mm < M_EXP; ++mm) l[mm] = 0.0f;
        for (int nb2 = 0; nb2 < FDIM / BN; ++nb2) {
            const float4* prr = reinterpret_cast<const float4*>(
                part + ((size_t)nb2 * BATCH + b) * M_EXP);
#pragma unroll
            for (int q = 0; q < 4; ++q) {
                const float4 v = prr[q];
                l[q * 4 + 0] += v.x;
                l[q * 4 + 1] += v.y;
                l[q * 4 + 2] += v.z;
                l[q * 4 + 3] += v.w;
            }
        }
        float mx = l[0];
#pragma unroll
        for (int mm = 1; mm < M_EXP; ++mm) mx = fmaxf(mx, l[mm]);
        float e[M_EXP], s = 0.0f;
#pragma unroll
        for (int mm = 0; mm < M_EXP; ++mm) { e[mm] = expf(l[mm] - mx); s += e[mm]; }
        const float inv = 1.0f / s;
#pragma unroll
        for (int mm = 0; mm < M_EXP; ++mm) out[OUT_PROBS + b * M_EXP + mm] = e[mm] * inv;

        int i0 = 0; float v0 = l[0];
#pragma unroll
        for (int mm = 1; mm < M_EXP; ++mm) if (l[mm] > v0) { v0 = l[mm]; i0 = mm; }
        int i1 = -1; float v1 = -INFINITY;
#pragma unroll
        for (int mm = 0; mm < M_EXP; ++mm) if (mm != i0 && l[mm] > v1) { v1 = l[mm]; i1 = mm; }

        const float t = expf(v1 - v0);
        const float g0 = 1.0f / (1.0f + t);
        const float g1 = t * g0;
#pragma unroll
        for (int mm = 0; mm < M_EXP; ++mm) out[OUT_GATES + b * M_EXP + mm] = 0.0f;
        out[OUT_GATES + b * M_EXP + i0] = g0;
        out[OUT_GATES + b * M_EXP + i1] = g1;
        out[OUT_IDX + b * 2 + 0] = (float)i0;
        out[OUT_IDX + b * 2 + 1] = (float)i1;
        if (b == 0) out[OUT_LOSS] = 0.0f;
    }
}

// ---------------------------------------------------------------------------
extern "C" void kernel_launch(void* const* d_in, const int* in_sizes, int n_in,
                              void* d_out, int out_size, void* d_ws, size_t ws_size,
                              hipStream_t stream) {
    const float* x        = (const float*)d_in[0];
    const float* degraded = (const float*)d_in[1];
    const float* w_fusion = (const float*)d_in[2];
    const float* b_fusion = (const float*)d_in[3];
    const float* w_gate   = (const float*)d_in[4];
    float* out = (float*)d_out;

    float* pslice = (float*)d_ws;                             // 16*256*1792 f32 (29.4 MB)
    float* pact2  = pslice + (size_t)NCH * BATCH * FDIM;      // 256*1792 f32    (1.84 MB)
    float* part   = pact2 + (size_t)BATCH * FDIM;             // 28*256*16 f32   (0.46 MB)
    int*   done   = (int*)(part + (size_t)28 * BATCH * M_EXP);

    hipMemsetAsync(done, 0, sizeof(int), stream);

    // 1) deg-GEMM (blocks 0..223) + pool+chunk-GEMM (blocks 224..4319)
    pool_gemm_kernel<<<GRID1, 256, 0, stream>>>(x, degraded, w_fusion, pslice, pact2);

    // 2) chunk-reduce + bias + gelu + gate partials + last-block finalize
    reduce_gate_kernel<<<dim3(BATCH / BM, FDIM / BN), 256, 0, stream>>>(pslice, pact2, b_fusion,
                                                                       w_gate, part, done, out);
}